// Round 8
// baseline (171.593 us; speedup 1.0000x reference)
//
#include <hip/hip_runtime.h>
#include <math.h>

#define N_NODES 40000
#define N_EDGES 640000
#define D 128
#define H 8
#define C 16
#define NBG 1250     // 40000/32 exactly
#define KP 136       // sA k-stride (bf16 elems)
#define NBUCK 2500   // 16-node buckets: bucket = dst >> 4 (40000 = 2500*16)
#define NCH 128      // chunks (5000 edges each)
#define ECH 5000     // edges per chunk (128*5000 = 640000)
#define CAP 8        // per-(bucket,chunk) slots; cell = exactly one 64-B line
#define SLOTS_B (NCH * CAP)   // 1024 slots (8 KB) per bucket
#define MAXB 384     // bucket-size bound (mean 256, sigma 16; 8-sigma guard)
#define OVCAP 4096   // global overflow list capacity (expect ~90 entries)
#define SOVC 64      // per-block overflow staging

typedef __attribute__((ext_vector_type(8))) short short8;   // 8 bf16 (4 VGPRs)
typedef __attribute__((ext_vector_type(4))) float floatx4;  // MFMA C/D

// ws layout (float offsets):
//  xh    : 0          .. 2,560,000   (N*128 bf16 stored as ushort)
//  al    : 5,120,000  .. 5,440,000   (N*8)
//  ar    : 5,440,000  .. 5,760,000   (N*8)
//  einfo : 6,000,000  .. 11,120,000  (NBUCK*SLOTS_B uint2 fixed cells;
//                                     einfo[(b*128+c)*8+r]={(src<<4)|dl, ew})
//  cnt2  : 11,500,000 .. 11,820,000  ([128][2500] ints, raw per-cell counts)
//  ovfn  : 12,000,000 (1 int)  ovf: 12,000,064 .. +4*OVCAP (uint4 entries)
//  wt    : 12,800,000 .. +16,384     (2x 128x128 bf16 transposed weights)

__device__ __forceinline__ unsigned short f2bf(float f) {
  const unsigned u = __float_as_uint(f);
  return (unsigned short)((u + 0x7FFFu + ((u >> 16) & 1u)) >> 16);  // RNE
}
__device__ __forceinline__ float bflo(unsigned p) {
  return __uint_as_float(p << 16);
}
__device__ __forceinline__ float bfhi(unsigned p) {
  return __uint_as_float(p & 0xFFFF0000u);
}
__device__ __forceinline__ float bf2f(unsigned short u) {
  return __uint_as_float((unsigned)u << 16);
}

// Pre-transpose W (fp32 [k][n]) -> wt (bf16 [g][n][k]). Also zeroes the
// overflow counter (runs before k_gemm in-stream).
__global__ void k_prep(const float* __restrict__ Wlin,
                       const float* __restrict__ Wres,
                       unsigned short* __restrict__ wt, int* __restrict__ ovfn)
{
  const int n = blockIdx.x, k = threadIdx.x, g = blockIdx.y;
  if (n == 0 && g == 0 && k == 0) *ovfn = 0;
  const float* W = g ? Wres : Wlin;
  wt[((g * 128 + n) * 128) + k] = f2bf(W[(long)k * 128 + n]);
}

// MFMA bf16 GEMM, 32-row blocks, BOTH weight matrices per block.
// blockIdx.y==0: xh=bf16(feat@Wlin) + fused alpha epilogue, outp=feat@Wres.
// blockIdx.y==1: count pass scattering einfo into fixed 64-B cells:
//   slot=(b*128+c)*8 + r (r = LDS rank). Rare r>=8 -> global overflow list.
__global__ __launch_bounds__(256, 4) void k_gemm(
    const float* __restrict__ feat, const unsigned short* __restrict__ wt,
    unsigned short* __restrict__ xh, float* __restrict__ outp,
    const float* __restrict__ attl, const float* __restrict__ attr,
    float* __restrict__ al, float* __restrict__ ar,
    const int* __restrict__ src, const int* __restrict__ dst,
    const float* __restrict__ ew, uint2* __restrict__ einfo,
    int* __restrict__ cnt2, int* __restrict__ ovfn, uint4* __restrict__ ovf)
{
  __shared__ short sA[32 * KP];     // 8,704 B
  __shared__ float sD[32 * 132];    // 16,896 B
  const int t = threadIdx.x;

  if (blockIdx.y == 1) {            // fused count + direct-scatter pass
    if (blockIdx.x >= NCH) return;
    int* lcnt = (int*)sD;           // 10,000 B (2500 bins)
    for (int i = t; i < NBUCK; i += 256) lcnt[i] = 0;
    __syncthreads();
    const int c = blockIdx.x;
    const int e0 = c * ECH;
    for (int e = e0 + t; e < e0 + ECH; e += 256) {
      const int d = dst[e];
      const int b = d >> 4, dl = d & 15;
      const int r = atomicAdd(&lcnt[b], 1);   // LDS atomic only
      const unsigned pay = ((unsigned)src[e] << 4) | (unsigned)dl;
      const unsigned wbits = __float_as_uint(ew[e]);
      if (r < CAP) {
        einfo[((long)b * NCH + c) * CAP + r] = make_uint2(pay, wbits);
      } else {                                 // ~90 expected edges total
        const int oi = atomicAdd(ovfn, 1);
        if (oi < OVCAP)
          ovf[oi] = make_uint4((unsigned)b, (unsigned)dl,
                               (unsigned)src[e], wbits);
      }
    }
    __syncthreads();
    for (int i = t; i < NBUCK; i += 256) cnt2[c * NBUCK + i] = lcnt[i];
    return;
  }

  const int row0 = blockIdx.x * 32;

  // stage A: 32 rows x 128 k, fp32 -> bf16 (coalesced float4 reads)
  {
    const int kq = t & 31;            // k = kq*4
    const int rb = (t >> 5) * 4;      // 4 rows per thread
    #pragma unroll
    for (int i = 0; i < 4; ++i) {
      const int r = rb + i;
      const float4 f = *(const float4*)&feat[(long)(row0 + r) * 128 + kq * 4];
      const unsigned lo = (unsigned)f2bf(f.x) | ((unsigned)f2bf(f.y) << 16);
      const unsigned hi = (unsigned)f2bf(f.z) | ((unsigned)f2bf(f.w) << 16);
      *(uint2*)&sA[r * KP + kq * 4] = make_uint2(lo, hi);
    }
  }

  const int w = t >> 6, lane = t & 63;
  const int c15 = lane & 15, q = lane >> 4;

  // B frags for both weight matrices: wave w owns n-tiles {2w, 2w+1}
  short8 bfr0[4][2], bfr1[4][2];
  #pragma unroll
  for (int kc = 0; kc < 4; ++kc)
    #pragma unroll
    for (int nt = 0; nt < 2; ++nt) {
      const int n = (w * 2 + nt) * 16 + c15;
      bfr0[kc][nt] = *(const short8*)&wt[n * 128 + kc * 32 + q * 8];
      bfr1[kc][nt] = *(const short8*)&wt[16384 + n * 128 + kc * 32 + q * 8];
    }
  __syncthreads();

  floatx4 acc0[2][2], acc1[2][2];
  #pragma unroll
  for (int mt = 0; mt < 2; ++mt)
    #pragma unroll
    for (int nt = 0; nt < 2; ++nt) {
      acc0[mt][nt] = (floatx4){0.f, 0.f, 0.f, 0.f};
      acc1[mt][nt] = (floatx4){0.f, 0.f, 0.f, 0.f};
    }
  #pragma unroll
  for (int kc = 0; kc < 4; ++kc)
    #pragma unroll
    for (int mt = 0; mt < 2; ++mt) {
      const short8 afr = *(const short8*)&sA[(mt * 16 + c15) * KP + kc * 32 + q * 8];
      acc0[mt][0] = __builtin_amdgcn_mfma_f32_16x16x32_bf16(afr, bfr0[kc][0], acc0[mt][0], 0, 0, 0);
      acc0[mt][1] = __builtin_amdgcn_mfma_f32_16x16x32_bf16(afr, bfr0[kc][1], acc0[mt][1], 0, 0, 0);
      acc1[mt][0] = __builtin_amdgcn_mfma_f32_16x16x32_bf16(afr, bfr1[kc][0], acc1[mt][0], 0, 0, 0);
      acc1[mt][1] = __builtin_amdgcn_mfma_f32_16x16x32_bf16(afr, bfr1[kc][1], acc1[mt][1], 0, 0, 0);
    }

  const int orow = t >> 3, seg = t & 7;
  const int grow = row0 + orow;

  // ---- pass 0: xh + alpha from acc0 ----
  #pragma unroll
  for (int mt = 0; mt < 2; ++mt)
    #pragma unroll
    for (int nt = 0; nt < 2; ++nt) {
      const int col = (w * 2 + nt) * 16 + c15;
      #pragma unroll
      for (int r = 0; r < 4; ++r)
        sD[(mt * 16 + q * 4 + r) * 132 + col] = acc0[mt][nt][r];
    }
  __syncthreads();
  {
    #pragma unroll
    for (int i = 0; i < 2; ++i) {     // 8 cols per iter
      const float4 v0 = *(const float4*)&sD[orow * 132 + seg * 16 + i * 8];
      const float4 v1 = *(const float4*)&sD[orow * 132 + seg * 16 + i * 8 + 4];
      uint4 u;
      u.x = (unsigned)f2bf(v0.x) | ((unsigned)f2bf(v0.y) << 16);
      u.y = (unsigned)f2bf(v0.z) | ((unsigned)f2bf(v0.w) << 16);
      u.z = (unsigned)f2bf(v1.x) | ((unsigned)f2bf(v1.y) << 16);
      u.w = (unsigned)f2bf(v1.z) | ((unsigned)f2bf(v1.w) << 16);
      *(uint4*)&xh[(long)grow * 128 + seg * 16 + i * 8] = u;
    }
    // fused alpha epilogue: thread = (node orow, head seg); one 16-dot each.
    const int h = seg;
    float sl = 0.f, sr = 0.f;
    #pragma unroll
    for (int c4 = 0; c4 < 4; ++c4) {
      const float4 xv = *(const float4*)&sD[orow * 132 + h * 16 + c4 * 4];
      const float4 lv = *(const float4*)&attl[h * 16 + c4 * 4];
      const float4 rv = *(const float4*)&attr[h * 16 + c4 * 4];
      sl += xv.x * lv.x + xv.y * lv.y + xv.z * lv.z + xv.w * lv.w;
      sr += xv.x * rv.x + xv.y * rv.y + xv.z * rv.z + xv.w * rv.w;
    }
    al[(long)grow * 8 + h] = sl;
    ar[(long)grow * 8 + h] = sr;
  }
  __syncthreads();

  // ---- pass 1: outp from acc1 ----
  #pragma unroll
  for (int mt = 0; mt < 2; ++mt)
    #pragma unroll
    for (int nt = 0; nt < 2; ++nt) {
      const int col = (w * 2 + nt) * 16 + c15;
      #pragma unroll
      for (int r = 0; r < 4; ++r)
        sD[(mt * 16 + q * 4 + r) * 132 + col] = acc1[mt][nt][r];
    }
  __syncthreads();
  #pragma unroll
  for (int i = 0; i < 4; ++i) {
    const float4 v = *(const float4*)&sD[orow * 132 + seg * 16 + i * 4];
    *(float4*)&outp[(long)grow * 128 + seg * 16 + i * 4] = v;
  }
}

// FUSED edge+aggregate: one 256-thread block per 16-node bucket (2500 blocks,
// 4 waves, ~9 KB LDS -> 8 blocks/CU).
//  sweep 1: coalesced 8-KB slot-window read, 16-bin count (LDS atomics).
//  scan: lanes 0-15 shuffle scan of bins.
//  sweep 2: re-read slots (L1/L2-hot), exp(logits) (al gathered L2-hot, ar in
//           LDS), counting-sort into sP/sS.
//  phase 4: per-node register aggregation (round-1-proven): wave wv owns 4
//           nodes; acc += pexp*x, ssum += pexp; normalize, ELU, residual RMW.
// pexp: no max subtraction (logits bounded ~|4|, softmax shift-invariant —
// validated in earlier rounds).
__global__ __launch_bounds__(256, 8) void k_edgeagg(
    const int* __restrict__ cnt2, const uint2* __restrict__ einfo,
    const int* __restrict__ ovfn, const uint4* __restrict__ ovf,
    const float* __restrict__ al, const float* __restrict__ ar,
    const unsigned short* __restrict__ xh, float* __restrict__ outp)
{
  __shared__ unsigned short sP[MAXB * 8];  // 6,144 B (sorted pexp, bf16)
  __shared__ int sS[MAXB];                 // 1,536 B (sorted src ids)
  __shared__ float sAr[128];               //   512 B (16 nodes x 8 heads)
  __shared__ int scnt[NCH];                //   512 B (clamped counts)
  __shared__ uint2 sOv[SOVC];              //   512 B (overflow staging)
  __shared__ int bcnt[16], bbase[16], bpos[16], nOv;
  const int b = blockIdx.x;
  const int t = threadIdx.x;
  if (t < 16) bcnt[t] = 0;
  if (t == 16) nOv = 0;
  if (t < 128) sAr[t] = ar[(long)(b << 4) * 8 + t];
  if (t >= 128) scnt[t - 128] = min(cnt2[(t - 128) * NBUCK + b], CAP);
  __syncthreads();

  const long base = (long)b * SLOTS_B;

  // sweep 1: count
  for (int i = t; i < SLOTS_B; i += 256) {
    const int c = i >> 3, r = i & 7;
    if (r < scnt[c]) {
      const uint2 m = einfo[base + i];
      atomicAdd(&bcnt[m.x & 15], 1);
    }
  }
  const int no = *ovfn;                    // normally ~0
  for (int i = t; i < no; i += 256) {
    const uint4 o = ovf[i];
    if ((int)o.x == b) {
      const int k = atomicAdd(&nOv, 1);
      if (k < SOVC) {
        sOv[k] = make_uint2((o.z << 4) | o.y, o.w);
        atomicAdd(&bcnt[o.y], 1);
      }
    }
  }
  __syncthreads();

  if (t < 16) {            // scan of 16 bins (lanes 0-15, wave 0)
    const int v = bcnt[t];
    int incl = v;
    #pragma unroll
    for (int off = 1; off < 16; off <<= 1) {
      const int n = __shfl_up(incl, off, 16);
      if (t >= off) incl += n;
    }
    bbase[t] = incl - v;
    bpos[t] = 0;
  }
  __syncthreads();

  // sweep 2: exp + counting sort (slot window is L1/L2-hot)
  auto process = [&](uint2 m) {
    const int dl = m.x & 15;
    const int s = (int)(m.x >> 4);
    const float w = __uint_as_float(m.y);
    const float4 l0 = *(const float4*)&al[(long)s * 8];
    const float4 l1 = *(const float4*)&al[(long)s * 8 + 4];
    const float* arr = &sAr[dl * 8];
    float lv[8] = {l0.x + arr[0], l0.y + arr[1], l0.z + arr[2], l0.w + arr[3],
                   l1.x + arr[4], l1.y + arr[5], l1.z + arr[6], l1.w + arr[7]};
    #pragma unroll
    for (int h = 0; h < 8; ++h) {
      float a = w * lv[h];
      a = (a >= 0.f) ? a : 0.2f * a;   // leaky_relu(0.2)
      lv[h] = __expf(a);
    }
    const int r = atomicAdd(&bpos[dl], 1);   // LDS atomic only
    const int qq = bbase[dl] + r;
    sS[qq] = s;
    uint4 u;
    u.x = (unsigned)f2bf(lv[0]) | ((unsigned)f2bf(lv[1]) << 16);
    u.y = (unsigned)f2bf(lv[2]) | ((unsigned)f2bf(lv[3]) << 16);
    u.z = (unsigned)f2bf(lv[4]) | ((unsigned)f2bf(lv[5]) << 16);
    u.w = (unsigned)f2bf(lv[6]) | ((unsigned)f2bf(lv[7]) << 16);
    *(uint4*)&sP[qq * 8] = u;
  };
  for (int i = t; i < SLOTS_B; i += 256) {
    const int c = i >> 3, r = i & 7;
    if (r < scnt[c]) process(einfo[base + i]);
  }
  const int nov = min(nOv, SOVC);
  for (int i = t; i < nov; i += 256) process(sOv[i]);
  __syncthreads();

  // phase 4: aggregation. wave wv handles nodes wv*4 .. wv*4+3.
  const int wv = t >> 6, lane = t & 63;
  const int h = lane >> 3;
  const int co = lane * 2;
  #pragma unroll
  for (int j = 0; j < 4; ++j) {
    const int dl = wv * 4 + j;
    const int start = bbase[dl];
    const int end = start + bcnt[dl];
    if (end <= start) continue;   // out already holds residual; elu(0)=0

    float2 a0 = {0.f, 0.f}, a1 = {0.f, 0.f}, a2 = {0.f, 0.f}, a3 = {0.f, 0.f};
    float s0s = 0.f, s1s = 0.f, s2s = 0.f, s3s = 0.f;
    int p = start;
    for (; p + 4 <= end; p += 4) {
      const int s0 = sS[p + 0], s1 = sS[p + 1];
      const int s2 = sS[p + 2], s3 = sS[p + 3];
      const float e0v = bf2f(sP[(p + 0) * 8 + h]);
      const float e1v = bf2f(sP[(p + 1) * 8 + h]);
      const float e2v = bf2f(sP[(p + 2) * 8 + h]);
      const float e3v = bf2f(sP[(p + 3) * 8 + h]);
      const unsigned v0 = *(const unsigned*)&xh[(long)s0 * 128 + co];
      const unsigned v1 = *(const unsigned*)&xh[(long)s1 * 128 + co];
      const unsigned v2 = *(const unsigned*)&xh[(long)s2 * 128 + co];
      const unsigned v3 = *(const unsigned*)&xh[(long)s3 * 128 + co];
      a0.x = fmaf(bflo(v0), e0v, a0.x); a0.y = fmaf(bfhi(v0), e0v, a0.y); s0s += e0v;
      a1.x = fmaf(bflo(v1), e1v, a1.x); a1.y = fmaf(bfhi(v1), e1v, a1.y); s1s += e1v;
      a2.x = fmaf(bflo(v2), e2v, a2.x); a2.y = fmaf(bfhi(v2), e2v, a2.y); s2s += e2v;
      a3.x = fmaf(bflo(v3), e3v, a3.x); a3.y = fmaf(bfhi(v3), e3v, a3.y); s3s += e3v;
    }
    for (; p < end; ++p) {
      const int s = sS[p];
      const float ev = bf2f(sP[p * 8 + h]);
      const unsigned v = *(const unsigned*)&xh[(long)s * 128 + co];
      a0.x = fmaf(bflo(v), ev, a0.x);
      a0.y = fmaf(bfhi(v), ev, a0.y);
      s0s += ev;
    }
    const float rs = 1.0f / ((s0s + s1s) + (s2s + s3s));
    const float ax = ((a0.x + a1.x) + (a2.x + a3.x)) * rs;
    const float ay = ((a0.y + a1.y) + (a2.y + a3.y)) * rs;

    const long dnode = (long)(b << 4) + dl;
    float2 o = *(float2*)&outp[dnode * 128 + co];
    o.x += (ax > 0.f) ? ax : expm1f(ax);
    o.y += (ay > 0.f) ? ay : expm1f(ay);
    *(float2*)&outp[dnode * 128 + co] = o;
  }
}

extern "C" void kernel_launch(void* const* d_in, const int* in_sizes, int n_in,
                              void* d_out, int out_size, void* d_ws, size_t ws_size,
                              hipStream_t stream) {
  const float* feat = (const float*)d_in[0];
  const int*   eidx = (const int*)d_in[1];
  const float* ew   = (const float*)d_in[2];
  const float* Wlin = (const float*)d_in[3];
  const float* attl = (const float*)d_in[4];
  const float* attr = (const float*)d_in[5];
  const float* Wres = (const float*)d_in[6];
  float* outp = (float*)d_out;

  float* ws = (float*)d_ws;
  unsigned short* xh = (unsigned short*)ws;
  float* al   = ws + 5120000;
  float* ar   = ws + 5440000;
  uint2* einfo = (uint2*)(ws + 6000000);   // NBUCK*SLOTS_B uint2 (20.5 MB)
  int*   cnt2 = (int*)(ws + 11500000);
  int*   ovfn = (int*)(ws + 12000000);
  uint4* ovf  = (uint4*)(ws + 12000064);
  unsigned short* wt = (unsigned short*)(ws + 12800000);

  const int* src = eidx;
  const int* dst = eidx + N_EDGES;

  dim3 pgrid(128, 2);
  k_prep<<<pgrid, 128, 0, stream>>>(Wlin, Wres, wt, ovfn);
  dim3 ggrid(NBG, 2);   // y=0 dual GEMM + alpha, y=1 count + direct scatter
  k_gemm<<<ggrid, 256, 0, stream>>>(feat, wt, xh, outp, attl, attr, al, ar,
                                    src, dst, ew, einfo, cnt2, ovfn, ovf);
  k_edgeagg<<<NBUCK, 256, 0, stream>>>(cnt2, einfo, ovfn, ovf, al, ar,
                                       xh, outp);
}

// Round 9
// 165.526 us; speedup vs baseline: 1.0367x; 1.0367x over previous
//
#include <hip/hip_runtime.h>
#include <math.h>

#define N_NODES 40000
#define N_EDGES 640000
#define D 128
#define H 8
#define C 16
#define NBG 1250     // 40000/32 exactly
#define KP 136       // sA k-stride (bf16 elems)
#define NBUCK 2500   // 16-node buckets: bucket = dst >> 4 (40000 = 2500*16)
#define NCH 512      // chunks (1250 edges each) — 512 count blocks, 2/CU
#define ECH 1250     // edges per chunk (512*1250 = 640000)
#define CAP 4        // per-(bucket,chunk) slots (32-B cell); lambda=0.5,
                     // P(overflow per cell) ~1.6e-4 -> ~210 edges to ovf list
#define SLOTS_B (NCH * CAP)   // 2048 slots (16 KB) per bucket
#define MAXB 384     // bucket-size bound (mean 256, sigma 16; 8-sigma guard)
#define OVCAP 4096   // global overflow list capacity
#define SOVC 64      // per-block overflow staging

typedef __attribute__((ext_vector_type(8))) short short8;   // 8 bf16 (4 VGPRs)
typedef __attribute__((ext_vector_type(4))) float floatx4;  // MFMA C/D

// ws layout (float offsets):
//  xh    : 0          .. 2,560,000   (N*128 bf16 stored as ushort)
//  al    : 5,120,000  .. 5,440,000   (N*8)
//  ar    : 5,440,000  .. 5,760,000   (N*8)
//  einfo : 6,000,000  .. 16,240,000  (NBUCK*SLOTS_B uint2 fixed cells;
//                                     einfo[(b*512+c)*4+r]={(src<<4)|dl, ew})
//  cnt2  : 16,300,000 .. 17,580,000  ([512][2500] ints, raw per-cell counts)
//  ovfn  : 17,600,000 (1 int)  ovf: 17,600,064 .. +4*OVCAP (uint4 entries)
//  wt    : 17,700,000 .. +16,384     (2x 128x128 bf16 transposed weights)

__device__ __forceinline__ unsigned short f2bf(float f) {
  const unsigned u = __float_as_uint(f);
  return (unsigned short)((u + 0x7FFFu + ((u >> 16) & 1u)) >> 16);  // RNE
}
__device__ __forceinline__ float bflo(unsigned p) {
  return __uint_as_float(p << 16);
}
__device__ __forceinline__ float bfhi(unsigned p) {
  return __uint_as_float(p & 0xFFFF0000u);
}
__device__ __forceinline__ float bf2f(unsigned short u) {
  return __uint_as_float((unsigned)u << 16);
}

// Pre-transpose W (fp32 [k][n]) -> wt (bf16 [g][n][k]). Also zeroes the
// overflow counter (runs before k_gemm in-stream).
__global__ void k_prep(const float* __restrict__ Wlin,
                       const float* __restrict__ Wres,
                       unsigned short* __restrict__ wt, int* __restrict__ ovfn)
{
  const int n = blockIdx.x, k = threadIdx.x, g = blockIdx.y;
  if (n == 0 && g == 0 && k == 0) *ovfn = 0;
  const float* W = g ? Wres : Wlin;
  wt[((g * 128 + n) * 128) + k] = f2bf(W[(long)k * 128 + n]);
}

// MFMA bf16 GEMM, 32-row blocks, BOTH weight matrices per block.
// blockIdx.y==0: xh=bf16(feat@Wlin) + fused alpha epilogue, outp=feat@Wres.
// blockIdx.y==1: count pass (512 blocks x 1250 edges — round-7-proven
//   parallelism) scattering einfo into fixed 32-B cells:
//   slot=(b*512+c)*4 + r (r = LDS rank). Rare r>=4 -> global overflow list.
__global__ __launch_bounds__(256, 4) void k_gemm(
    const float* __restrict__ feat, const unsigned short* __restrict__ wt,
    unsigned short* __restrict__ xh, float* __restrict__ outp,
    const float* __restrict__ attl, const float* __restrict__ attr,
    float* __restrict__ al, float* __restrict__ ar,
    const int* __restrict__ src, const int* __restrict__ dst,
    const float* __restrict__ ew, uint2* __restrict__ einfo,
    int* __restrict__ cnt2, int* __restrict__ ovfn, uint4* __restrict__ ovf)
{
  __shared__ short sA[32 * KP];     // 8,704 B
  __shared__ float sD[32 * 132];    // 16,896 B
  const int t = threadIdx.x;

  if (blockIdx.y == 1) {            // fused count + direct-scatter pass
    if (blockIdx.x >= NCH) return;
    int* lcnt = (int*)sD;           // 10,000 B (2500 bins)
    for (int i = t; i < NBUCK; i += 256) lcnt[i] = 0;
    __syncthreads();
    const int c = blockIdx.x;
    const int e0 = c * ECH;
    for (int e = e0 + t; e < e0 + ECH; e += 256) {
      const int d = dst[e];
      const int b = d >> 4, dl = d & 15;
      const int r = atomicAdd(&lcnt[b], 1);   // LDS atomic only
      const unsigned pay = ((unsigned)src[e] << 4) | (unsigned)dl;
      const unsigned wbits = __float_as_uint(ew[e]);
      if (r < CAP) {
        einfo[((long)b * NCH + c) * CAP + r] = make_uint2(pay, wbits);
      } else {                                 // ~210 expected edges total
        const int oi = atomicAdd(ovfn, 1);
        if (oi < OVCAP)
          ovf[oi] = make_uint4((unsigned)b, (unsigned)dl,
                               (unsigned)src[e], wbits);
      }
    }
    __syncthreads();
    for (int i = t; i < NBUCK; i += 256) cnt2[c * NBUCK + i] = lcnt[i];
    return;
  }

  const int row0 = blockIdx.x * 32;

  // stage A: 32 rows x 128 k, fp32 -> bf16 (coalesced float4 reads)
  {
    const int kq = t & 31;            // k = kq*4
    const int rb = (t >> 5) * 4;      // 4 rows per thread
    #pragma unroll
    for (int i = 0; i < 4; ++i) {
      const int r = rb + i;
      const float4 f = *(const float4*)&feat[(long)(row0 + r) * 128 + kq * 4];
      const unsigned lo = (unsigned)f2bf(f.x) | ((unsigned)f2bf(f.y) << 16);
      const unsigned hi = (unsigned)f2bf(f.z) | ((unsigned)f2bf(f.w) << 16);
      *(uint2*)&sA[r * KP + kq * 4] = make_uint2(lo, hi);
    }
  }

  const int w = t >> 6, lane = t & 63;
  const int c15 = lane & 15, q = lane >> 4;

  // B frags for both weight matrices: wave w owns n-tiles {2w, 2w+1}
  short8 bfr0[4][2], bfr1[4][2];
  #pragma unroll
  for (int kc = 0; kc < 4; ++kc)
    #pragma unroll
    for (int nt = 0; nt < 2; ++nt) {
      const int n = (w * 2 + nt) * 16 + c15;
      bfr0[kc][nt] = *(const short8*)&wt[n * 128 + kc * 32 + q * 8];
      bfr1[kc][nt] = *(const short8*)&wt[16384 + n * 128 + kc * 32 + q * 8];
    }
  __syncthreads();

  floatx4 acc0[2][2], acc1[2][2];
  #pragma unroll
  for (int mt = 0; mt < 2; ++mt)
    #pragma unroll
    for (int nt = 0; nt < 2; ++nt) {
      acc0[mt][nt] = (floatx4){0.f, 0.f, 0.f, 0.f};
      acc1[mt][nt] = (floatx4){0.f, 0.f, 0.f, 0.f};
    }
  #pragma unroll
  for (int kc = 0; kc < 4; ++kc)
    #pragma unroll
    for (int mt = 0; mt < 2; ++mt) {
      const short8 afr = *(const short8*)&sA[(mt * 16 + c15) * KP + kc * 32 + q * 8];
      acc0[mt][0] = __builtin_amdgcn_mfma_f32_16x16x32_bf16(afr, bfr0[kc][0], acc0[mt][0], 0, 0, 0);
      acc0[mt][1] = __builtin_amdgcn_mfma_f32_16x16x32_bf16(afr, bfr0[kc][1], acc0[mt][1], 0, 0, 0);
      acc1[mt][0] = __builtin_amdgcn_mfma_f32_16x16x32_bf16(afr, bfr1[kc][0], acc1[mt][0], 0, 0, 0);
      acc1[mt][1] = __builtin_amdgcn_mfma_f32_16x16x32_bf16(afr, bfr1[kc][1], acc1[mt][1], 0, 0, 0);
    }

  const int orow = t >> 3, seg = t & 7;
  const int grow = row0 + orow;

  // ---- pass 0: xh + alpha from acc0 ----
  #pragma unroll
  for (int mt = 0; mt < 2; ++mt)
    #pragma unroll
    for (int nt = 0; nt < 2; ++nt) {
      const int col = (w * 2 + nt) * 16 + c15;
      #pragma unroll
      for (int r = 0; r < 4; ++r)
        sD[(mt * 16 + q * 4 + r) * 132 + col] = acc0[mt][nt][r];
    }
  __syncthreads();
  {
    #pragma unroll
    for (int i = 0; i < 2; ++i) {     // 8 cols per iter
      const float4 v0 = *(const float4*)&sD[orow * 132 + seg * 16 + i * 8];
      const float4 v1 = *(const float4*)&sD[orow * 132 + seg * 16 + i * 8 + 4];
      uint4 u;
      u.x = (unsigned)f2bf(v0.x) | ((unsigned)f2bf(v0.y) << 16);
      u.y = (unsigned)f2bf(v0.z) | ((unsigned)f2bf(v0.w) << 16);
      u.z = (unsigned)f2bf(v1.x) | ((unsigned)f2bf(v1.y) << 16);
      u.w = (unsigned)f2bf(v1.z) | ((unsigned)f2bf(v1.w) << 16);
      *(uint4*)&xh[(long)grow * 128 + seg * 16 + i * 8] = u;
    }
    // fused alpha epilogue: thread = (node orow, head seg); one 16-dot each.
    const int h = seg;
    float sl = 0.f, sr = 0.f;
    #pragma unroll
    for (int c4 = 0; c4 < 4; ++c4) {
      const float4 xv = *(const float4*)&sD[orow * 132 + h * 16 + c4 * 4];
      const float4 lv = *(const float4*)&attl[h * 16 + c4 * 4];
      const float4 rv = *(const float4*)&attr[h * 16 + c4 * 4];
      sl += xv.x * lv.x + xv.y * lv.y + xv.z * lv.z + xv.w * lv.w;
      sr += xv.x * rv.x + xv.y * rv.y + xv.z * rv.z + xv.w * rv.w;
    }
    al[(long)grow * 8 + h] = sl;
    ar[(long)grow * 8 + h] = sr;
  }
  __syncthreads();

  // ---- pass 1: outp from acc1 ----
  #pragma unroll
  for (int mt = 0; mt < 2; ++mt)
    #pragma unroll
    for (int nt = 0; nt < 2; ++nt) {
      const int col = (w * 2 + nt) * 16 + c15;
      #pragma unroll
      for (int r = 0; r < 4; ++r)
        sD[(mt * 16 + q * 4 + r) * 132 + col] = acc1[mt][nt][r];
    }
  __syncthreads();
  #pragma unroll
  for (int i = 0; i < 4; ++i) {
    const float4 v = *(const float4*)&sD[orow * 132 + seg * 16 + i * 4];
    *(float4*)&outp[(long)grow * 128 + seg * 16 + i * 4] = v;
  }
}

// FUSED edge+aggregate: one 256-thread block per 16-node bucket (2500 blocks,
// 4 waves, ~11 KB LDS -> 8 blocks/CU).
//  sweep 1: coalesced 16-KB slot-window read, 16-bin count (LDS atomics).
//  scan: lanes 0-15 shuffle scan of bins.
//  sweep 2: re-read slots (L1/L2-hot), exp(logits) (al gathered L2-hot, ar in
//           LDS), counting-sort into sP/sS.
//  phase 4: per-node register aggregation (round-1-proven): wave wv owns 4
//           nodes; acc += pexp*x, ssum += pexp; normalize, ELU, residual RMW.
// pexp: no max subtraction (logits bounded ~|4|, softmax shift-invariant —
// validated in earlier rounds).
__global__ __launch_bounds__(256, 8) void k_edgeagg(
    const int* __restrict__ cnt2, const uint2* __restrict__ einfo,
    const int* __restrict__ ovfn, const uint4* __restrict__ ovf,
    const float* __restrict__ al, const float* __restrict__ ar,
    const unsigned short* __restrict__ xh, float* __restrict__ outp)
{
  __shared__ unsigned short sP[MAXB * 8];  // 6,144 B (sorted pexp, bf16)
  __shared__ int sS[MAXB];                 // 1,536 B (sorted src ids)
  __shared__ float sAr[128];               //   512 B (16 nodes x 8 heads)
  __shared__ int scnt[NCH];                // 2,048 B (clamped counts)
  __shared__ uint2 sOv[SOVC];              //   512 B (overflow staging)
  __shared__ int bcnt[16], bbase[16], bpos[16], nOv;
  const int b = blockIdx.x;
  const int t = threadIdx.x;
  if (t < 16) bcnt[t] = 0;
  if (t == 16) nOv = 0;
  if (t < 128) sAr[t] = ar[(long)(b << 4) * 8 + t];
  for (int i = t; i < NCH; i += 256)
    scnt[i] = min(cnt2[i * NBUCK + b], CAP);
  __syncthreads();

  const long base = (long)b * SLOTS_B;

  // sweep 1: count
  for (int i = t; i < SLOTS_B; i += 256) {
    const int c = i >> 2, r = i & 3;
    if (r < scnt[c]) {
      const uint2 m = einfo[base + i];
      atomicAdd(&bcnt[m.x & 15], 1);
    }
  }
  const int no = *ovfn;                    // normally ~200 chip-wide
  for (int i = t; i < no; i += 256) {
    const uint4 o = ovf[i];
    if ((int)o.x == b) {
      const int k = atomicAdd(&nOv, 1);
      if (k < SOVC) {
        sOv[k] = make_uint2((o.z << 4) | o.y, o.w);
        atomicAdd(&bcnt[o.y], 1);
      }
    }
  }
  __syncthreads();

  if (t < 16) {            // scan of 16 bins (lanes 0-15, wave 0)
    const int v = bcnt[t];
    int incl = v;
    #pragma unroll
    for (int off = 1; off < 16; off <<= 1) {
      const int n = __shfl_up(incl, off, 16);
      if (t >= off) incl += n;
    }
    bbase[t] = incl - v;
    bpos[t] = 0;
  }
  __syncthreads();

  // sweep 2: exp + counting sort (slot window is L1/L2-hot)
  auto process = [&](uint2 m) {
    const int dl = m.x & 15;
    const int s = (int)(m.x >> 4);
    const float w = __uint_as_float(m.y);
    const float4 l0 = *(const float4*)&al[(long)s * 8];
    const float4 l1 = *(const float4*)&al[(long)s * 8 + 4];
    const float* arr = &sAr[dl * 8];
    float lv[8] = {l0.x + arr[0], l0.y + arr[1], l0.z + arr[2], l0.w + arr[3],
                   l1.x + arr[4], l1.y + arr[5], l1.z + arr[6], l1.w + arr[7]};
    #pragma unroll
    for (int h = 0; h < 8; ++h) {
      float a = w * lv[h];
      a = (a >= 0.f) ? a : 0.2f * a;   // leaky_relu(0.2)
      lv[h] = __expf(a);
    }
    const int r = atomicAdd(&bpos[dl], 1);   // LDS atomic only
    const int qq = bbase[dl] + r;
    sS[qq] = s;
    uint4 u;
    u.x = (unsigned)f2bf(lv[0]) | ((unsigned)f2bf(lv[1]) << 16);
    u.y = (unsigned)f2bf(lv[2]) | ((unsigned)f2bf(lv[3]) << 16);
    u.z = (unsigned)f2bf(lv[4]) | ((unsigned)f2bf(lv[5]) << 16);
    u.w = (unsigned)f2bf(lv[6]) | ((unsigned)f2bf(lv[7]) << 16);
    *(uint4*)&sP[qq * 8] = u;
  };
  for (int i = t; i < SLOTS_B; i += 256) {
    const int c = i >> 2, r = i & 3;
    if (r < scnt[c]) process(einfo[base + i]);
  }
  const int nov = min(nOv, SOVC);
  for (int i = t; i < nov; i += 256) process(sOv[i]);
  __syncthreads();

  // phase 4: aggregation. wave wv handles nodes wv*4 .. wv*4+3.
  const int wv = t >> 6, lane = t & 63;
  const int h = lane >> 3;
  const int co = lane * 2;
  #pragma unroll
  for (int j = 0; j < 4; ++j) {
    const int dl = wv * 4 + j;
    const int start = bbase[dl];
    const int end = start + bcnt[dl];
    if (end <= start) continue;   // out already holds residual; elu(0)=0

    float2 a0 = {0.f, 0.f}, a1 = {0.f, 0.f}, a2 = {0.f, 0.f}, a3 = {0.f, 0.f};
    float s0s = 0.f, s1s = 0.f, s2s = 0.f, s3s = 0.f;
    int p = start;
    for (; p + 4 <= end; p += 4) {
      const int s0 = sS[p + 0], s1 = sS[p + 1];
      const int s2 = sS[p + 2], s3 = sS[p + 3];
      const float e0v = bf2f(sP[(p + 0) * 8 + h]);
      const float e1v = bf2f(sP[(p + 1) * 8 + h]);
      const float e2v = bf2f(sP[(p + 2) * 8 + h]);
      const float e3v = bf2f(sP[(p + 3) * 8 + h]);
      const unsigned v0 = *(const unsigned*)&xh[(long)s0 * 128 + co];
      const unsigned v1 = *(const unsigned*)&xh[(long)s1 * 128 + co];
      const unsigned v2 = *(const unsigned*)&xh[(long)s2 * 128 + co];
      const unsigned v3 = *(const unsigned*)&xh[(long)s3 * 128 + co];
      a0.x = fmaf(bflo(v0), e0v, a0.x); a0.y = fmaf(bfhi(v0), e0v, a0.y); s0s += e0v;
      a1.x = fmaf(bflo(v1), e1v, a1.x); a1.y = fmaf(bfhi(v1), e1v, a1.y); s1s += e1v;
      a2.x = fmaf(bflo(v2), e2v, a2.x); a2.y = fmaf(bfhi(v2), e2v, a2.y); s2s += e2v;
      a3.x = fmaf(bflo(v3), e3v, a3.x); a3.y = fmaf(bfhi(v3), e3v, a3.y); s3s += e3v;
    }
    for (; p < end; ++p) {
      const int s = sS[p];
      const float ev = bf2f(sP[p * 8 + h]);
      const unsigned v = *(const unsigned*)&xh[(long)s * 128 + co];
      a0.x = fmaf(bflo(v), ev, a0.x);
      a0.y = fmaf(bfhi(v), ev, a0.y);
      s0s += ev;
    }
    const float rs = 1.0f / ((s0s + s1s) + (s2s + s3s));
    const float ax = ((a0.x + a1.x) + (a2.x + a3.x)) * rs;
    const float ay = ((a0.y + a1.y) + (a2.y + a3.y)) * rs;

    const long dnode = (long)(b << 4) + dl;
    float2 o = *(float2*)&outp[dnode * 128 + co];
    o.x += (ax > 0.f) ? ax : expm1f(ax);
    o.y += (ay > 0.f) ? ay : expm1f(ay);
    *(float2*)&outp[dnode * 128 + co] = o;
  }
}

extern "C" void kernel_launch(void* const* d_in, const int* in_sizes, int n_in,
                              void* d_out, int out_size, void* d_ws, size_t ws_size,
                              hipStream_t stream) {
  const float* feat = (const float*)d_in[0];
  const int*   eidx = (const int*)d_in[1];
  const float* ew   = (const float*)d_in[2];
  const float* Wlin = (const float*)d_in[3];
  const float* attl = (const float*)d_in[4];
  const float* attr = (const float*)d_in[5];
  const float* Wres = (const float*)d_in[6];
  float* outp = (float*)d_out;

  float* ws = (float*)d_ws;
  unsigned short* xh = (unsigned short*)ws;
  float* al   = ws + 5120000;
  float* ar   = ws + 5440000;
  uint2* einfo = (uint2*)(ws + 6000000);   // NBUCK*SLOTS_B uint2 (40.9 MB)
  int*   cnt2 = (int*)(ws + 16300000);
  int*   ovfn = (int*)(ws + 17600000);
  uint4* ovf  = (uint4*)(ws + 17600064);
  unsigned short* wt = (unsigned short*)(ws + 17700000);

  const int* src = eidx;
  const int* dst = eidx + N_EDGES;

  dim3 pgrid(128, 2);
  k_prep<<<pgrid, 128, 0, stream>>>(Wlin, Wres, wt, ovfn);
  dim3 ggrid(NBG, 2);   // y=0 dual GEMM + alpha, y=1 count + direct scatter
  k_gemm<<<ggrid, 256, 0, stream>>>(feat, wt, xh, outp, attl, attr, al, ar,
                                    src, dst, ew, einfo, cnt2, ovfn, ovf);
  k_edgeagg<<<NBUCK, 256, 0, stream>>>(cnt2, einfo, ovfn, ovf, al, ar,
                                       xh, outp);
}